// Round 5
// baseline (2132.064 us; speedup 1.0000x reference)
//
#include <hip/hip_runtime.h>
#include <hip/hip_fp16.h>

#define B_ 256
#define S_ 512
#define D_ 200
#define H_ 256

typedef _Float16 half2_t __attribute__((ext_vector_type(2)));
typedef _Float16 half4_t __attribute__((ext_vector_type(4)));
typedef _Float16 half8_t __attribute__((ext_vector_type(8)));
typedef float    floatx4 __attribute__((ext_vector_type(4)));

__device__ __forceinline__ float fast_sig(float x) {
    return 1.f / (1.f + __expf(-x));
}
__device__ __forceinline__ float fast_tanh(float x) {
    x = fminf(15.f, fmaxf(-15.f, x));
    float e = __expf(2.f * x);
    return (e - 1.f) / (e + 1.f);
}

// ---------------------------------------------------------------------------
// prep: build fp16 weight layouts in workspace.
//   W4T [1024][224]: W4T[n][k] = Wg[k][j] (x-part rows 0..199, zero-padded)
//   WhT [1024][256]: WhT[n][k] = Wg[200+k][j] (h-part), n = g*256+j
// ---------------------------------------------------------------------------
__global__ void prep(const float* __restrict__ Wi, const float* __restrict__ Wf,
                     const float* __restrict__ Wo, const float* __restrict__ Wz,
                     _Float16* __restrict__ W4T, _Float16* __restrict__ WhT) {
    const int n = blockIdx.x;      // 0..1023
    const int t = threadIdx.x;     // 0..255
    const int g = n >> 8, j = n & 255;
    const float* Wg = (g == 0) ? Wi : (g == 1) ? Wf : (g == 2) ? Wo : Wz;
    if (t < 224)
        W4T[(size_t)n * 224 + t] = (t < D_) ? (_Float16)Wg[t * 256 + j] : (_Float16)0.f;
    WhT[(size_t)n * 256 + t] = (_Float16)Wg[(D_ + t) * 256 + j];
}

// ---------------------------------------------------------------------------
// gemm_x: G[m][n] = sum_k X[m][k]*W4T[n][k] + bias[n]   (unchanged, verified)
// ---------------------------------------------------------------------------
__global__ __launch_bounds__(256) void gemm_x(const float* __restrict__ X,
                                              const _Float16* __restrict__ W4T,
                                              const float* __restrict__ bi,
                                              const float* __restrict__ bfg,
                                              const float* __restrict__ bo,
                                              const float* __restrict__ bz,
                                              _Float16* __restrict__ G) {
    __shared__ __align__(16) _Float16 As[128][40];
    __shared__ __align__(16) _Float16 Bs[128][40];

    const int mt = blockIdx.x >> 3;
    const int nt = blockIdx.x & 7;
    const int m0 = mt * 128, n0 = nt * 128;
    const int tid  = threadIdx.x;
    const int lane = tid & 63, wave = tid >> 6;
    const int quad = lane >> 4, l16 = lane & 15;
    const int mq = (wave & 1) * 64, nq = (wave >> 1) * 64;

    floatx4 acc[4][4];
#pragma unroll
    for (int i = 0; i < 4; ++i)
#pragma unroll
        for (int j = 0; j < 4; ++j) acc[i][j] = (floatx4){0.f, 0.f, 0.f, 0.f};

    const int srow = tid >> 1;
    const int koff = (tid & 1) * 16;

    for (int kt = 0; kt < 7; ++kt) {
        const int k0 = kt * 32;
        {
            const int m = m0 + srow;
            const float* xr = X + (size_t)m * D_ + (k0 + koff);
            half8_t v0, v1;
            if (m < B_ * S_ - 1) {
                const floatx4* xp = (const floatx4*)xr;
                floatx4 f0 = xp[0], f1 = xp[1], f2 = xp[2], f3 = xp[3];
#pragma unroll
                for (int i = 0; i < 4; ++i) {
                    v0[i]     = (_Float16)f0[i];
                    v0[4 + i] = (_Float16)f1[i];
                    v1[i]     = (_Float16)f2[i];
                    v1[4 + i] = (_Float16)f3[i];
                }
            } else {
#pragma unroll
                for (int i = 0; i < 8; ++i) {
                    int k = k0 + koff + i;
                    v0[i] = (k < D_) ? (_Float16)xr[i] : (_Float16)0.f;
                }
#pragma unroll
                for (int i = 0; i < 8; ++i) {
                    int k = k0 + koff + 8 + i;
                    v1[i] = (k < D_) ? (_Float16)xr[8 + i] : (_Float16)0.f;
                }
            }
            *(half8_t*)&As[srow][koff]     = v0;
            *(half8_t*)&As[srow][koff + 8] = v1;
        }
        {
            const _Float16* wr = W4T + (size_t)(n0 + srow) * 224 + (k0 + koff);
            const half8_t* wp = (const half8_t*)wr;
            *(half8_t*)&Bs[srow][koff]     = wp[0];
            *(half8_t*)&Bs[srow][koff + 8] = wp[1];
        }
        __syncthreads();

        half8_t af[4], bf[4];
#pragma unroll
        for (int i = 0; i < 4; ++i) af[i] = *(const half8_t*)&As[mq + i * 16 + l16][quad * 8];
#pragma unroll
        for (int i = 0; i < 4; ++i) bf[i] = *(const half8_t*)&Bs[nq + i * 16 + l16][quad * 8];
#pragma unroll
        for (int mi = 0; mi < 4; ++mi)
#pragma unroll
            for (int ni = 0; ni < 4; ++ni)
                acc[mi][ni] = __builtin_amdgcn_mfma_f32_16x16x32_f16(af[mi], bf[ni], acc[mi][ni], 0, 0, 0);
        __syncthreads();
    }

#pragma unroll
    for (int ni = 0; ni < 4; ++ni) {
        const int gcol = n0 + nq + ni * 16 + l16;
        const int g = gcol >> 8, j = gcol & 255;
        const float bv = ((g == 0) ? bi : (g == 1) ? bfg : (g == 2) ? bo : bz)[j];
#pragma unroll
        for (int mi = 0; mi < 4; ++mi)
#pragma unroll
            for (int r = 0; r < 4; ++r) {
                const int grow = m0 + mq + mi * 16 + quad * 4 + r;
                G[(size_t)grow * 1024 + gcol] = (_Float16)(acc[mi][ni][r] + bv);
            }
    }
}

// ---------------------------------------------------------------------------
// lstm_rec6: single-block-per-batch recurrence (round-0 structure) with the
// A-LDS reads SOFTWARE-PIPELINED under the register-MFMA bursts.
//   Round-0 audit: MFMA 2483cy + LDS ~1950cy + tail ~450 == measured 4875cy
//   step => ZERO pipe overlap.  Cause: the 16 A-LDS reads/wave were direct
//   MFMA operands bunched in a late window (C-accumulator chains serialize
//   MFALL(4,5) behind them), so the LDS window and MFMA window serialize.
//   Fix: 2-frag register pairs, issue pair k one MFALL burst before its
//   consume; the C-chain sandwich (MFALL(k-1) -> consume-k -> MFALL(k))
//   enforces the coarse order, asm pins anchor the load issue points.
//   Bv6/Bv7 read first (feed the early pairs); Bv4/5 staggered mid-step to
//   offset the +16 VGPR staging cost.  Everything else verbatim round-0.
// ---------------------------------------------------------------------------
__global__ __launch_bounds__(512, 2) void lstm_rec6(
    const _Float16* __restrict__ G,     // [B][S][1024] plain, bias folded
    const _Float16* __restrict__ WhT,   // [1024][256] fp16
    const float* __restrict__ mask,     // [B][S] fp32
    float* __restrict__ out)            // [B][256] fp32
{
    __shared__ __align__(16) half8_t  WLfrag[8192];   // 128 KB
    __shared__ __align__(16) _Float16 hS[2][256];     // 1 KB

    const int b    = blockIdx.x;
    const int t    = threadIdx.x;   // 0..511
    const int w    = t >> 6;        // wave 0..7
    const int lane = t & 63;
    const int l16  = lane & 15, quad = lane >> 4;

    // ---- stage LDS A-fragments (k in [192,256)) in fragment order ----
#pragma unroll
    for (int mi = 0; mi < 8; ++mi) {
        const int gcol = ((mi & 3) << 8) + (2 * w + (mi >> 2)) * 16 + l16;
        const half8_t* src = (const half8_t*)(WhT + (size_t)gcol * 256);
        WLfrag[((w * 8 + mi) * 2 + 0) * 64 + lane] = src[6 * 4 + quad];
        WLfrag[((w * 8 + mi) * 2 + 1) * 64 + lane] = src[7 * 4 + quad];
    }

    // ---- register A-fragments: k in [0,192), 48 named pinned half8 ----
#define DECLF(mi) half8_t F##mi##_0, F##mi##_1, F##mi##_2, F##mi##_3, F##mi##_4, F##mi##_5
#define LOADF(mi) do {                                                        \
        const int gcol = ((mi & 3) << 8) + (2 * w + ((mi) >> 2)) * 16 + l16;  \
        const half8_t* p = (const half8_t*)(WhT + (size_t)gcol * 256);        \
        F##mi##_0 = p[0 * 4 + quad]; F##mi##_1 = p[1 * 4 + quad];             \
        F##mi##_2 = p[2 * 4 + quad]; F##mi##_3 = p[3 * 4 + quad];             \
        F##mi##_4 = p[4 * 4 + quad]; F##mi##_5 = p[5 * 4 + quad];             \
        asm volatile("" : "+v"(F##mi##_0), "+v"(F##mi##_1), "+v"(F##mi##_2),  \
                          "+v"(F##mi##_3), "+v"(F##mi##_4), "+v"(F##mi##_5)); \
    } while (0)
    DECLF(0); DECLF(1); DECLF(2); DECLF(3); DECLF(4); DECLF(5); DECLF(6); DECLF(7);
    LOADF(0); LOADF(1); LOADF(2); LOADF(3); LOADF(4); LOADF(5); LOADF(6); LOADF(7);

    if (t < 256) hS[0][t] = (_Float16)0.f;

    const int jbh_c = (l16 >> 2) & 1;
    const int r_c   = l16 & 3;
    const int j     = 32 * w + jbh_c * 16 + quad * 4 + r_c;

    float cst = 0.f, accum = 0.f, msum = 0.f;
    const float* mb = mask + (size_t)b * S_;

    const _Float16* Gbase = G + ((size_t)b << 19) + 32 * w + quad * 4;

    half4_t N0, N1, N2, N3, N4, N5, N6, N7;
#define GLOAD(sidx) do {                                                      \
        const _Float16* gp = Gbase + ((size_t)(sidx) << 10);                  \
        N0 = *(const half4_t*)(gp + 0);   N1 = *(const half4_t*)(gp + 256);   \
        N2 = *(const half4_t*)(gp + 512); N3 = *(const half4_t*)(gp + 768);   \
        N4 = *(const half4_t*)(gp + 16);  N5 = *(const half4_t*)(gp + 272);   \
        N6 = *(const half4_t*)(gp + 528); N7 = *(const half4_t*)(gp + 784);   \
    } while (0)

    GLOAD(0);
    __syncthreads();

#define MFALL(kt, Bv)                                                          \
    C0 = __builtin_amdgcn_mfma_f32_16x16x32_f16(F0_##kt, Bv, C0, 0, 0, 0);     \
    C1 = __builtin_amdgcn_mfma_f32_16x16x32_f16(F1_##kt, Bv, C1, 0, 0, 0);     \
    C2 = __builtin_amdgcn_mfma_f32_16x16x32_f16(F2_##kt, Bv, C2, 0, 0, 0);     \
    C3 = __builtin_amdgcn_mfma_f32_16x16x32_f16(F3_##kt, Bv, C3, 0, 0, 0);     \
    C4 = __builtin_amdgcn_mfma_f32_16x16x32_f16(F4_##kt, Bv, C4, 0, 0, 0);     \
    C5 = __builtin_amdgcn_mfma_f32_16x16x32_f16(F5_##kt, Bv, C5, 0, 0, 0);     \
    C6 = __builtin_amdgcn_mfma_f32_16x16x32_f16(F6_##kt, Bv, C6, 0, 0, 0);     \
    C7 = __builtin_amdgcn_mfma_f32_16x16x32_f16(F7_##kt, Bv, C7, 0, 0, 0)

// issue one staged A-LDS pair (2 x ds_read_b128) and anchor the issue point
#define WLD(v0, v1, mi0, mi1, ktL)                                             \
    half8_t v0 = WLfrag[((w * 8 + (mi0)) * 2 + (ktL)) * 64 + lane];            \
    half8_t v1 = WLfrag[((w * 8 + (mi1)) * 2 + (ktL)) * 64 + lane];            \
    asm volatile("" : "+v"(v0), "+v"(v1))

// consume one staged pair
#define MFP(Ra, Rb, Ca, Cb, Bv)                                                \
    Ca = __builtin_amdgcn_mfma_f32_16x16x32_f16(Ra, Bv, Ca, 0, 0, 0);          \
    Cb = __builtin_amdgcn_mfma_f32_16x16x32_f16(Rb, Bv, Cb, 0, 0, 0)

    for (int s = 0; s < S_; ++s) {
        const float m = mb[s];
        const _Float16* hb = hS[s & 1];

        // 1) B ds_reads: Bv6/Bv7 first (feed the staged pairs), then Bv0..3
        half8_t Bv6 = *(const half8_t*)(hb + 6 * 32 + quad * 8);
        half8_t Bv7 = *(const half8_t*)(hb + 7 * 32 + quad * 8);
        half8_t Bv0 = *(const half8_t*)(hb + 0 * 32 + quad * 8);
        half8_t Bv1 = *(const half8_t*)(hb + 1 * 32 + quad * 8);
        half8_t Bv2 = *(const half8_t*)(hb + 2 * 32 + quad * 8);
        half8_t Bv3 = *(const half8_t*)(hb + 3 * 32 + quad * 8);

        // 2) pair0 issue (kt=6 -> ktL 0, consumed with Bv6)
        WLD(R0, R1, 0, 1, 0);

        // 3) C init from prefetched G gather (covers pair0 + Bv latency)
        floatx4 C0, C1, C2, C3, C4, C5, C6, C7;
#pragma unroll
        for (int k = 0; k < 4; ++k) {
            C0[k] = (float)N0[k]; C1[k] = (float)N1[k];
            C2[k] = (float)N2[k]; C3[k] = (float)N3[k];
            C4[k] = (float)N4[k]; C5[k] = (float)N5[k];
            C6[k] = (float)N6[k]; C7[k] = (float)N7[k];
        }
        // 4) prefetch next step's G (regs free after the cvts)
        GLOAD((s < S_ - 1) ? s + 1 : s);

        // 5) MFMA phase: A-LDS pairs streamed under the MFALL bursts.
        WLD(R2, R3, 2, 3, 0);
        MFP(R0, R1, C0, C1, Bv6);
        MFALL(0, Bv0);
        WLD(R4, R5, 4, 5, 0);
        MFP(R2, R3, C2, C3, Bv6);
        MFALL(1, Bv1);
        half8_t Bv4 = *(const half8_t*)(hb + 4 * 32 + quad * 8);
        half8_t Bv5 = *(const half8_t*)(hb + 5 * 32 + quad * 8);
        WLD(R6, R7, 6, 7, 0);
        MFP(R4, R5, C4, C5, Bv6);
        MFALL(2, Bv2);
        WLD(S0, S1, 0, 1, 1);
        MFP(R6, R7, C6, C7, Bv6);
        MFALL(3, Bv3);
        WLD(S2, S3, 2, 3, 1);
        MFP(S0, S1, C0, C1, Bv7);
        MFALL(4, Bv4);
        WLD(S4, S5, 4, 5, 1);
        MFP(S2, S3, C2, C3, Bv7);
        MFALL(5, Bv5);
        WLD(S6, S7, 6, 7, 1);
        MFP(S4, S5, C4, C5, Bv7);
        MFP(S6, S7, C6, C7, Bv7);

        // 6) gate select: pre_g = C[jbh_c*4 + g][r_c]
        floatx4 s0 = jbh_c ? C4 : C0;
        floatx4 s1 = jbh_c ? C5 : C1;
        floatx4 s2 = jbh_c ? C6 : C2;
        floatx4 s3 = jbh_c ? C7 : C3;
        float pre0, pre1, pre2, pre3;
        {
            float v01 = (r_c & 1) ? s0[1] : s0[0], v23 = (r_c & 1) ? s0[3] : s0[2];
            pre0 = (r_c & 2) ? v23 : v01;
            v01 = (r_c & 1) ? s1[1] : s1[0]; v23 = (r_c & 1) ? s1[3] : s1[2];
            pre1 = (r_c & 2) ? v23 : v01;
            v01 = (r_c & 1) ? s2[1] : s2[0]; v23 = (r_c & 1) ? s2[3] : s2[2];
            pre2 = (r_c & 2) ? v23 : v01;
            v01 = (r_c & 1) ? s3[1] : s3[0]; v23 = (r_c & 1) ? s3[3] : s3[2];
            pre3 = (r_c & 2) ? v23 : v01;
        }
        const float fi = fast_sig(pre0);
        const float ff = fast_sig(pre1);
        const float fo = fast_sig(pre2);
        const float fz = fast_tanh(pre3);
        cst = fi * fz + ff * cst;
        const float h = fo * fast_tanh(cst);
        accum += m * h;
        msum  += m;
        if (l16 < 8) hS[(s + 1) & 1][j] = (_Float16)h;
        __syncthreads();
    }
#undef MFALL
#undef MFP
#undef WLD
#undef DECLF
#undef LOADF
#undef GLOAD

    if (l16 < 8) out[b * 256 + j] = accum / msum;
}

extern "C" void kernel_launch(void* const* d_in, const int* in_sizes, int n_in,
                              void* d_out, int out_size, void* d_ws, size_t ws_size,
                              hipStream_t stream) {
    const float* X    = (const float*)d_in[0];
    const float* mask = (const float*)d_in[1];
    const float* Wi   = (const float*)d_in[2];
    const float* bi   = (const float*)d_in[3];
    const float* Wf   = (const float*)d_in[4];
    const float* bf   = (const float*)d_in[5];
    const float* Wo   = (const float*)d_in[6];
    const float* bo   = (const float*)d_in[7];
    const float* Wz   = (const float*)d_in[8];
    const float* bz   = (const float*)d_in[9];
    float* out = (float*)d_out;

    char* ws = (char*)d_ws;
    _Float16* G   = (_Float16*)ws;                                   // 268,435,456 B
    _Float16* W4T = (_Float16*)(ws + (size_t)B_ * S_ * 1024 * 2);    //     458,752 B
    _Float16* WhT = (_Float16*)(ws + (size_t)B_ * S_ * 1024 * 2 + (size_t)1024 * 224 * 2);

    hipLaunchKernelGGL(prep,      dim3(1024), dim3(256), 0, stream, Wi, Wf, Wo, Wz, W4T, WhT);
    hipLaunchKernelGGL(gemm_x,    dim3(8192), dim3(256), 0, stream, X, W4T, bi, bf, bo, bz, G);
    hipLaunchKernelGGL(lstm_rec6, dim3(B_),   dim3(512), 0, stream, G, WhT, mask, out);
}